// Round 5
// baseline (380.047 us; speedup 1.0000x reference)
//
#include <hip/hip_runtime.h>
#include <math.h>

typedef __attribute__((ext_vector_type(8))) short short8;
typedef __attribute__((ext_vector_type(4))) float v4f;
typedef __attribute__((ext_vector_type(4))) unsigned short us4;

#define INV_SCALE 0.07216878364870322f  // 1/sqrt(64*3)

__device__ __forceinline__ unsigned short f2bf(float f) {
  unsigned u = __builtin_bit_cast(unsigned, f);
  u = (u + 0x7FFFu + ((u >> 16) & 1u)) >> 16;  // RNE
  return (unsigned short)u;
}
__device__ __forceinline__ float bf2f(unsigned short h) {
  unsigned u = ((unsigned)h) << 16;
  return __builtin_bit_cast(float, u);
}

enum { OM_PLAIN = 0, OM_Q = 1, OM_K = 2, OM_VT = 3, OM_PK = 4, OM_PQ = 5 };

// -----------------------------------------------------------------------------
// One-time: transpose all 6 weight matrices (384x384 fp32 [k][n]) to bf16
// [n][k] so GEMM B reads are contiguous. Wt = 6 x 384 x 384 bf16.
// -----------------------------------------------------------------------------
__global__ __launch_bounds__(256) void transpose_w(
    const float* __restrict__ Wq, const float* __restrict__ Wk,
    const float* __restrict__ Wv, const float* __restrict__ Wpk,
    const float* __restrict__ Wpq, const float* __restrict__ Wo,
    unsigned short* __restrict__ Wt) {
  __shared__ unsigned short Ts[64][68];
  const int mat = blockIdx.y;
  const float* W = mat == 0 ? Wq : mat == 1 ? Wk : mat == 2 ? Wv
                 : mat == 3 ? Wpk : mat == 4 ? Wpq : Wo;
  const int tk = (blockIdx.x % 6) * 64, tn = (blockIdx.x / 6) * 64;
  const int t = threadIdx.x;
#pragma unroll
  for (int it = 0; it < 4; ++it) {
    int r = (t >> 4) + it * 16, c = (t & 15) * 4;
    float4 v = *(const float4*)(W + (size_t)(tk + r) * 384 + tn + c);
    us4 p = {f2bf(v.x), f2bf(v.y), f2bf(v.z), f2bf(v.w)};
    *(us4*)&Ts[r][c] = p;
  }
  __syncthreads();
  unsigned short* out = Wt + (size_t)mat * 147456;
#pragma unroll
  for (int it = 0; it < 2; ++it) {
    int n = (t >> 3) + it * 32, kc = (t & 7) * 8;
    unsigned short tmp[8];
#pragma unroll
    for (int j = 0; j < 8; ++j) tmp[j] = Ts[kc + j][n];
    *(short8*)(out + (size_t)(tn + n) * 384 + tk + kc) = *(short8*)tmp;
  }
}

// -----------------------------------------------------------------------------
// GEMM body (unchanged): out = A(Mx384) @ Wt_panel^T (+bias)*scale.
// Tile 64x64; wave w -> rows [w*16,w*16+16).
// -----------------------------------------------------------------------------
template <typename AT, int OMODE>
__device__ __forceinline__ void pgemm_body(
    const AT* __restrict__ A, const unsigned short* __restrict__ Bt,
    const float* __restrict__ bias, void* __restrict__ out,
    int m0, int n0, float scale, unsigned short (*Bs)[392]) {
  const int t = threadIdx.x;
  const int lane = t & 63, w = t >> 6, li = lane & 15, quad = lane >> 4;

  {
    int r = t >> 2, cq = (t & 3) * 96;
#pragma unroll
    for (int i = 0; i < 12; ++i)
      *(short8*)&Bs[r][cq + i * 8] =
          *(const short8*)(Bt + (size_t)(n0 + r) * 384 + cq + i * 8);
  }
  const int row = m0 + w * 16 + li;
  short8 afr[12];
#pragma unroll
  for (int kk = 0; kk < 12; ++kk) {
    if constexpr (sizeof(AT) == 4) {
      float4 u0 = *(const float4*)((const float*)A + (size_t)row * 384 + kk * 32 + quad * 8);
      float4 u1 = *(const float4*)((const float*)A + (size_t)row * 384 + kk * 32 + quad * 8 + 4);
      short8 v;
      v[0] = (short)f2bf(u0.x); v[1] = (short)f2bf(u0.y);
      v[2] = (short)f2bf(u0.z); v[3] = (short)f2bf(u0.w);
      v[4] = (short)f2bf(u1.x); v[5] = (short)f2bf(u1.y);
      v[6] = (short)f2bf(u1.z); v[7] = (short)f2bf(u1.w);
      afr[kk] = v;
    } else {
      afr[kk] = *(const short8*)((const unsigned short*)A + (size_t)row * 384 + kk * 32 + quad * 8);
    }
  }
  __syncthreads();

  v4f acc[4] = {};
#pragma unroll
  for (int kk = 0; kk < 12; ++kk) {
#pragma unroll
    for (int nt = 0; nt < 4; ++nt) {
      short8 bf = *(const short8*)&Bs[nt * 16 + li][kk * 32 + quad * 8];
      acc[nt] = __builtin_amdgcn_mfma_f32_16x16x32_bf16(afr[kk], bf, acc[nt], 0, 0, 0);
    }
  }

#pragma unroll
  for (int nt = 0; nt < 4; ++nt) {
    int col = n0 + nt * 16 + li;
    float bv = bias[col];
    int h = col >> 6, d = col & 63;
#pragma unroll
    for (int i = 0; i < 4; ++i) {
      int orow = m0 + w * 16 + quad * 4 + i;
      float val = (acc[nt][i] + bv) * scale;
      if constexpr (OMODE == OM_PLAIN) {
        ((float*)out)[(size_t)orow * 384 + col] = val;
      } else if constexpr (OMODE == OM_Q || OMODE == OM_K) {
        int b = orow >> 10, n = orow & 1023;
        ((unsigned short*)out)[((size_t)(b * 6 + h) << 16) + (n << 6) + d] = f2bf(val);
      } else if constexpr (OMODE == OM_VT) {
        int b = orow >> 10, n = orow & 1023;
        ((unsigned short*)out)[((size_t)(b * 6 + h) << 16) + (d << 10) + n] = f2bf(val);
      } else {  // OM_PK / OM_PQ: [h][p][d]
        ((unsigned short*)out)[(size_t)h * 49152 + (size_t)orow * 64 + d] = f2bf(val);
      }
    }
  }
}

__global__ __launch_bounds__(256, 3) void proj_all(
    const float* __restrict__ x, const float* __restrict__ re,
    const unsigned short* __restrict__ Wt,
    const float* __restrict__ bq, const float* __restrict__ bk,
    const float* __restrict__ bv, const float* __restrict__ bpk,
    const float* __restrict__ bpq,
    unsigned short* __restrict__ qw, unsigned short* __restrict__ kw,
    unsigned short* __restrict__ vtw, unsigned short* __restrict__ pkw,
    unsigned short* __restrict__ pqw) {
  __shared__ __align__(16) unsigned short Bs[64][392];
  const int which = blockIdx.y / 6;
  const int n0 = (blockIdx.y % 6) * 64;
  const int m0 = blockIdx.x * 64;
  if (which >= 3 && m0 >= 768) return;
  const float* A = which < 3 ? x : re;
  const unsigned short* Bt = Wt + (size_t)which * 147456;
  switch (which) {
    case 0: pgemm_body<float, OM_Q >(A, Bt, bq,  qw,  m0, n0, INV_SCALE, Bs); break;
    case 1: pgemm_body<float, OM_K >(A, Bt, bk,  kw,  m0, n0, 1.f, Bs); break;
    case 2: pgemm_body<float, OM_VT>(A, Bt, bv,  vtw, m0, n0, 1.f, Bs); break;
    case 3: pgemm_body<float, OM_PK>(A, Bt, bpk, pkw, m0, n0, 1.f, Bs); break;
    default: pgemm_body<float, OM_PQ>(A, Bt, bpq, pqw, m0, n0, INV_SCALE, Bs); break;
  }
}

__global__ __launch_bounds__(256, 3) void out_gemm(
    const unsigned short* __restrict__ ao, const unsigned short* __restrict__ Bt,
    const float* __restrict__ bo, float* __restrict__ out) {
  __shared__ __align__(16) unsigned short Bs[64][392];
  pgemm_body<unsigned short, OM_PLAIN>(ao, Bt, bo, out,
                                       blockIdx.x * 64, blockIdx.y * 64, 1.f, Bs);
}

// -----------------------------------------------------------------------------
// Fused disentangled attention — ROUND-7: BARRIER/LDS-PHASE RESTRUCTURE.
//
// R4 evidence: conflicts 1.3e7->5.5e6 yet dur 146->153.7 us => bank conflicts
// are NOT the critical path; 4 barriers/tile serializing dependency chains
// (all pipes <25% busy) are. Changes vs the 146 us structure:
//  1. NO band staging: T1/T2 B-frags read directly from global pk/pq
//     (1.2 MB, L1/L2-resident) with per-lane clamped row. Deletes the stage
//     phase (8 ds_write_b128) and all 32 B-frag ds_read_b128 per wave/tile.
//     Register residency stays lean (aq0/aq1 only persistent; t1a dies
//     before t2a lives) -- unlike R2's spilling variant.
//  2. band1 (T1^T) is WAVE-PRIVATE BY COLUMNS: gather reads band1[r][nl]
//     with nl in [w*16, w*16+16) = exactly the columns wave w writes.
//     T1^T writes need NO barrier (within-wave DS ordering suffices).
//  3. Only T2^T (cols jl span all 64) is cross-wave: barriers 4 -> 2 per
//     tile (A: prev gather done before overwrite; B: T2^T visible).
//  4. BSW swizzle kept where banking needs it (us4 T^T writes would be
//     16-way on linear [128][64]; gather ~2-way with swizzle).
// LDS 40960 B (band1/band2 128x64, Ps 64x64); 3 blocks/CU.
// -----------------------------------------------------------------------------
#define BSW(r, c) ((c) ^ (((r) & 7) << 3))  // short-index swizzle in 64-wide row

__global__ __launch_bounds__(256, 3) void attn_fused(
    const unsigned short* __restrict__ q, const unsigned short* __restrict__ k,
    const unsigned short* __restrict__ vt, const unsigned short* __restrict__ pk,
    const unsigned short* __restrict__ pq, unsigned short* __restrict__ ao) {
  __shared__ __align__(16) unsigned short band1[128][64];  // T1^T (wave-private cols)
  __shared__ __align__(16) unsigned short band2[128][64];  // T2^T (cross-wave)
  __shared__ __align__(16) unsigned short Ps[64][64];

  const int bh = blockIdx.y;
  const int h = bh % 6, b = bh / 6;
  const int n0 = blockIdx.x * 64;
  const int t = threadIdx.x;
  const int lane = t & 63, w = t >> 6;
  const int li = lane & 15, quad = lane >> 4;

  const unsigned short* qb = q + ((size_t)bh << 16);
  const unsigned short* kb = k + ((size_t)bh << 16);
  const unsigned short* vb = vt + ((size_t)bh << 16);
  const unsigned short* pkh = pk + (size_t)h * 49152;
  const unsigned short* pqh = pq + (size_t)h * 49152;

  // q A-frags: loaded once (q pre-scaled by INV_SCALE)
  short8 aq0 = *(const short8*)(qb + (size_t)(n0 + w * 16 + li) * 64 + quad * 8);
  short8 aq1 = *(const short8*)(qb + (size_t)(n0 + w * 16 + li) * 64 + 32 + quad * 8);

  float l_part[4] = {0.f, 0.f, 0.f, 0.f};
  v4f o[4] = {};

  for (int j0 = 0; j0 < 1024; j0 += 64) {
    const int pb = n0 - j0 + 321;  // band row r -> pos row clamp(pb + r)

    // ---- T1 = q' @ pk_rows^T (B-frags direct from global; wave-private cols)
    {
      v4f t1a[8] = {};
#pragma unroll
      for (int ct = 0; ct < 8; ++ct) {
        const int brow = ct * 16 + li;
        int src = pb + brow;
        src = src < 0 ? 0 : (src > 767 ? 767 : src);
        short8 b0 = *(const short8*)(pkh + (size_t)src * 64 + quad * 8);
        short8 b1 = *(const short8*)(pkh + (size_t)src * 64 + 32 + quad * 8);
        t1a[ct] = __builtin_amdgcn_mfma_f32_16x16x32_bf16(aq0, b0, t1a[ct], 0, 0, 0);
        t1a[ct] = __builtin_amdgcn_mfma_f32_16x16x32_bf16(aq1, b1, t1a[ct], 0, 0, 0);
      }
      // no barrier: wave w's gather only ever reads cols [w*16, w*16+16),
      // which only wave w writes; same-wave DS ops are ordered.
#pragma unroll
      for (int ct = 0; ct < 8; ++ct) {
        const int brow = ct * 16 + li;
        us4 p1 = {f2bf(t1a[ct][0]), f2bf(t1a[ct][1]), f2bf(t1a[ct][2]), f2bf(t1a[ct][3])};
        *(us4*)&band1[brow][BSW(brow, w * 16 + quad * 4)] = p1;
      }
    }

    // ---- T2 = k @ pq_rows^T (A = own k-rows; B direct from global) ----
    short8 ak0 = *(const short8*)(kb + (size_t)(j0 + w * 16 + li) * 64 + quad * 8);
    short8 ak1 = *(const short8*)(kb + (size_t)(j0 + w * 16 + li) * 64 + 32 + quad * 8);
    v4f t2a[8] = {};
#pragma unroll
    for (int ct = 0; ct < 8; ++ct) {
      const int brow = ct * 16 + li;
      int src = pb + brow;
      src = src < 0 ? 0 : (src > 767 ? 767 : src);
      short8 b0 = *(const short8*)(pqh + (size_t)src * 64 + quad * 8);
      short8 b1 = *(const short8*)(pqh + (size_t)src * 64 + 32 + quad * 8);
      t2a[ct] = __builtin_amdgcn_mfma_f32_16x16x32_bf16(ak0, b0, t2a[ct], 0, 0, 0);
      t2a[ct] = __builtin_amdgcn_mfma_f32_16x16x32_bf16(ak1, b1, t2a[ct], 0, 0, 0);
    }

    // ---- S_qk (B-frags = k rows direct from global/L1) ----
    v4f sqk[4] = {};
#pragma unroll
    for (int nt = 0; nt < 4; ++nt) {
      short8 b0 = *(const short8*)(kb + (size_t)(j0 + nt * 16 + li) * 64 + quad * 8);
      short8 b1 = *(const short8*)(kb + (size_t)(j0 + nt * 16 + li) * 64 + 32 + quad * 8);
      sqk[nt] = __builtin_amdgcn_mfma_f32_16x16x32_bf16(aq0, b0, sqk[nt], 0, 0, 0);
      sqk[nt] = __builtin_amdgcn_mfma_f32_16x16x32_bf16(aq1, b1, sqk[nt], 0, 0, 0);
    }

    __syncthreads();  // A: all waves done gathering previous tile's band2
#pragma unroll
    for (int ct = 0; ct < 8; ++ct) {
      const int brow = ct * 16 + li;
      us4 p2 = {f2bf(t2a[ct][0]), f2bf(t2a[ct][1]), f2bf(t2a[ct][2]), f2bf(t2a[ct][3])};
      *(us4*)&band2[brow][BSW(brow, w * 16 + quad * 4)] = p2;
    }
    __syncthreads();  // B: T2^T visible cross-wave

    // ---- gather + exp (scale pre-folded) + Ps ----
#pragma unroll
    for (int nt = 0; nt < 4; ++nt) {
      int jl = nt * 16 + li;
#pragma unroll
      for (int i = 0; i < 4; ++i) {
        int nl = w * 16 + quad * 4 + i;
        int r = nl - jl + 63;
        float s = sqk[nt][i] + bf2f(band1[r][BSW(r, nl)]) + bf2f(band2[r][BSW(r, jl)]);
        float p = __expf(s);
        l_part[i] += p;
        Ps[nl][BSW(nl, jl)] = f2bf(p);
      }
    }
    // ---- PV (A-frag Ps: same-wave rows; B-frag vt direct from global) ----
#pragma unroll
    for (int kst = 0; kst < 2; ++kst) {
      const int prow = w * 16 + li;
      short8 ap = *(const short8*)&Ps[prow][BSW(prow, kst * 32 + quad * 8)];
#pragma unroll
      for (int nt = 0; nt < 4; ++nt) {
        short8 bv2 = *(const short8*)(vb + (size_t)(nt * 16 + li) * 1024 + j0 + kst * 32 + quad * 8);
        o[nt] = __builtin_amdgcn_mfma_f32_16x16x32_bf16(ap, bv2, o[nt], 0, 0, 0);
      }
    }
  }

  // final: reduce l across the 16 col-lanes, normalize, store (B,N,C) bf16
#pragma unroll
  for (int i = 0; i < 4; ++i) {
    float l = l_part[i];
    l += __shfl_xor(l, 1);
    l += __shfl_xor(l, 2);
    l += __shfl_xor(l, 4);
    l += __shfl_xor(l, 8);
    float inv_l = 1.f / l;
    int nl = w * 16 + quad * 4 + i;
#pragma unroll
    for (int nt = 0; nt < 4; ++nt)
      ao[((size_t)(b * 1024 + n0 + nl)) * 384 + h * 64 + nt * 16 + li] =
          f2bf(o[nt][i] * inv_l);
  }
}

// -----------------------------------------------------------------------------
extern "C" void kernel_launch(void* const* d_in, const int* in_sizes, int n_in,
                              void* d_out, int out_size, void* d_ws,
                              size_t ws_size, hipStream_t stream) {
  const float* x   = (const float*)d_in[0];
  const float* re  = (const float*)d_in[2];
  const float* Wq  = (const float*)d_in[3];
  const float* bq  = (const float*)d_in[4];
  const float* Wk  = (const float*)d_in[5];
  const float* bk  = (const float*)d_in[6];
  const float* Wv  = (const float*)d_in[7];
  const float* bv  = (const float*)d_in[8];
  const float* Wpk = (const float*)d_in[9];
  const float* bpk = (const float*)d_in[10];
  const float* Wpq = (const float*)d_in[11];
  const float* bpq = (const float*)d_in[12];
  const float* Wo  = (const float*)d_in[13];
  const float* bo  = (const float*)d_in[14];
  float* out = (float*)d_out;

  unsigned short* ws = (unsigned short*)d_ws;
  unsigned short* Wt  = ws;                 // 6*384*384
  unsigned short* qw  = Wt + 884736;        // 48*1024*64 (pre-scaled)
  unsigned short* kw  = qw + 3145728;
  unsigned short* vtw = kw + 3145728;       // (B,H,D,N)
  unsigned short* pkw = vtw + 3145728;      // 6*768*64
  unsigned short* pqw = pkw + 294912;       // (pre-scaled)
  unsigned short* aow = pqw + 294912;       // 8192*384 bf16

  transpose_w<<<dim3(36, 6), 256, 0, stream>>>(Wq, Wk, Wv, Wpk, Wpq, Wo, Wt);
  proj_all<<<dim3(128, 30), 256, 0, stream>>>(x, re, Wt, bq, bk, bv, bpk, bpq,
                                              qw, kw, vtw, pkw, pqw);
  attn_fused<<<dim3(16, 48), 256, 0, stream>>>(qw, kw, vtw, pkw, pqw, aow);
  out_gemm<<<dim3(128, 6), 256, 0, stream>>>(aow, Wt + 5 * 147456, bo, out);
}

// Round 8
// 271.637 us; speedup vs baseline: 1.3991x; 1.3991x over previous
//
#include <hip/hip_runtime.h>
#include <math.h>

typedef __attribute__((ext_vector_type(8))) short short8;
typedef __attribute__((ext_vector_type(4))) float v4f;
typedef __attribute__((ext_vector_type(4))) unsigned short us4;

#define INV_SCALE 0.07216878364870322f  // 1/sqrt(64*3)

__device__ __forceinline__ unsigned short f2bf(float f) {
  unsigned u = __builtin_bit_cast(unsigned, f);
  u = (u + 0x7FFFu + ((u >> 16) & 1u)) >> 16;  // RNE
  return (unsigned short)u;
}
__device__ __forceinline__ float bf2f(unsigned short h) {
  unsigned u = ((unsigned)h) << 16;
  return __builtin_bit_cast(float, u);
}

enum { OM_PLAIN = 0, OM_Q = 1, OM_K = 2, OM_VT = 3, OM_PK = 4, OM_PQ = 5 };

// -----------------------------------------------------------------------------
// One-time: transpose all 6 weight matrices (384x384 fp32 [k][n]) to bf16
// [n][k] so GEMM B reads are contiguous. Wt = 6 x 384 x 384 bf16.
// -----------------------------------------------------------------------------
__global__ __launch_bounds__(256) void transpose_w(
    const float* __restrict__ Wq, const float* __restrict__ Wk,
    const float* __restrict__ Wv, const float* __restrict__ Wpk,
    const float* __restrict__ Wpq, const float* __restrict__ Wo,
    unsigned short* __restrict__ Wt) {
  __shared__ unsigned short Ts[64][68];
  const int mat = blockIdx.y;
  const float* W = mat == 0 ? Wq : mat == 1 ? Wk : mat == 2 ? Wv
                 : mat == 3 ? Wpk : mat == 4 ? Wpq : Wo;
  const int tk = (blockIdx.x % 6) * 64, tn = (blockIdx.x / 6) * 64;
  const int t = threadIdx.x;
#pragma unroll
  for (int it = 0; it < 4; ++it) {
    int r = (t >> 4) + it * 16, c = (t & 15) * 4;
    float4 v = *(const float4*)(W + (size_t)(tk + r) * 384 + tn + c);
    us4 p = {f2bf(v.x), f2bf(v.y), f2bf(v.z), f2bf(v.w)};
    *(us4*)&Ts[r][c] = p;
  }
  __syncthreads();
  unsigned short* out = Wt + (size_t)mat * 147456;
#pragma unroll
  for (int it = 0; it < 2; ++it) {
    int n = (t >> 3) + it * 32, kc = (t & 7) * 8;
    unsigned short tmp[8];
#pragma unroll
    for (int j = 0; j < 8; ++j) tmp[j] = Ts[kc + j][n];
    *(short8*)(out + (size_t)(tn + n) * 384 + tk + kc) = *(short8*)tmp;
  }
}

// -----------------------------------------------------------------------------
// GEMM body (unchanged): out = A(Mx384) @ Wt_panel^T (+bias)*scale.
// Tile 64x64; wave w -> rows [w*16,w*16+16).
// -----------------------------------------------------------------------------
template <typename AT, int OMODE>
__device__ __forceinline__ void pgemm_body(
    const AT* __restrict__ A, const unsigned short* __restrict__ Bt,
    const float* __restrict__ bias, void* __restrict__ out,
    int m0, int n0, float scale, unsigned short (*Bs)[392]) {
  const int t = threadIdx.x;
  const int lane = t & 63, w = t >> 6, li = lane & 15, quad = lane >> 4;

  {
    int r = t >> 2, cq = (t & 3) * 96;
#pragma unroll
    for (int i = 0; i < 12; ++i)
      *(short8*)&Bs[r][cq + i * 8] =
          *(const short8*)(Bt + (size_t)(n0 + r) * 384 + cq + i * 8);
  }
  const int row = m0 + w * 16 + li;
  short8 afr[12];
#pragma unroll
  for (int kk = 0; kk < 12; ++kk) {
    if constexpr (sizeof(AT) == 4) {
      float4 u0 = *(const float4*)((const float*)A + (size_t)row * 384 + kk * 32 + quad * 8);
      float4 u1 = *(const float4*)((const float*)A + (size_t)row * 384 + kk * 32 + quad * 8 + 4);
      short8 v;
      v[0] = (short)f2bf(u0.x); v[1] = (short)f2bf(u0.y);
      v[2] = (short)f2bf(u0.z); v[3] = (short)f2bf(u0.w);
      v[4] = (short)f2bf(u1.x); v[5] = (short)f2bf(u1.y);
      v[6] = (short)f2bf(u1.z); v[7] = (short)f2bf(u1.w);
      afr[kk] = v;
    } else {
      afr[kk] = *(const short8*)((const unsigned short*)A + (size_t)row * 384 + kk * 32 + quad * 8);
    }
  }
  __syncthreads();

  v4f acc[4] = {};
#pragma unroll
  for (int kk = 0; kk < 12; ++kk) {
#pragma unroll
    for (int nt = 0; nt < 4; ++nt) {
      short8 bf = *(const short8*)&Bs[nt * 16 + li][kk * 32 + quad * 8];
      acc[nt] = __builtin_amdgcn_mfma_f32_16x16x32_bf16(afr[kk], bf, acc[nt], 0, 0, 0);
    }
  }

#pragma unroll
  for (int nt = 0; nt < 4; ++nt) {
    int col = n0 + nt * 16 + li;
    float bv = bias[col];
    int h = col >> 6, d = col & 63;
#pragma unroll
    for (int i = 0; i < 4; ++i) {
      int orow = m0 + w * 16 + quad * 4 + i;
      float val = (acc[nt][i] + bv) * scale;
      if constexpr (OMODE == OM_PLAIN) {
        ((float*)out)[(size_t)orow * 384 + col] = val;
      } else if constexpr (OMODE == OM_Q || OMODE == OM_K) {
        int b = orow >> 10, n = orow & 1023;
        ((unsigned short*)out)[((size_t)(b * 6 + h) << 16) + (n << 6) + d] = f2bf(val);
      } else if constexpr (OMODE == OM_VT) {
        int b = orow >> 10, n = orow & 1023;
        ((unsigned short*)out)[((size_t)(b * 6 + h) << 16) + (d << 10) + n] = f2bf(val);
      } else {  // OM_PK / OM_PQ: [h][p][d]
        ((unsigned short*)out)[(size_t)h * 49152 + (size_t)orow * 64 + d] = f2bf(val);
      }
    }
  }
}

__global__ __launch_bounds__(256, 3) void proj_all(
    const float* __restrict__ x, const float* __restrict__ re,
    const unsigned short* __restrict__ Wt,
    const float* __restrict__ bq, const float* __restrict__ bk,
    const float* __restrict__ bv, const float* __restrict__ bpk,
    const float* __restrict__ bpq,
    unsigned short* __restrict__ qw, unsigned short* __restrict__ kw,
    unsigned short* __restrict__ vtw, unsigned short* __restrict__ pkw,
    unsigned short* __restrict__ pqw) {
  __shared__ __align__(16) unsigned short Bs[64][392];
  const int which = blockIdx.y / 6;
  const int n0 = (blockIdx.y % 6) * 64;
  const int m0 = blockIdx.x * 64;
  if (which >= 3 && m0 >= 768) return;
  const float* A = which < 3 ? x : re;
  const unsigned short* Bt = Wt + (size_t)which * 147456;
  switch (which) {
    case 0: pgemm_body<float, OM_Q >(A, Bt, bq,  qw,  m0, n0, INV_SCALE, Bs); break;
    case 1: pgemm_body<float, OM_K >(A, Bt, bk,  kw,  m0, n0, 1.f, Bs); break;
    case 2: pgemm_body<float, OM_VT>(A, Bt, bv,  vtw, m0, n0, 1.f, Bs); break;
    case 3: pgemm_body<float, OM_PK>(A, Bt, bpk, pkw, m0, n0, 1.f, Bs); break;
    default: pgemm_body<float, OM_PQ>(A, Bt, bpq, pqw, m0, n0, INV_SCALE, Bs); break;
  }
}

__global__ __launch_bounds__(256, 3) void out_gemm(
    const unsigned short* __restrict__ ao, const unsigned short* __restrict__ Bt,
    const float* __restrict__ bo, float* __restrict__ out) {
  __shared__ __align__(16) unsigned short Bs[64][392];
  pgemm_body<unsigned short, OM_PLAIN>(ao, Bt, bo, out,
                                       blockIdx.x * 64, blockIdx.y * 64, 1.f, Bs);
}

// -----------------------------------------------------------------------------
// Fused disentangled attention — ROUND-8 RESUBMIT x2 (R6/R7 were broker
// timeouts; kernel never ran). The 146 us ROUND-4 STRUCTURE VERBATIM
// (ASTR=72, LDS band staging, 4 barriers, register-lean) plus two
// structure-preserving latency fixes:
//
//  1. XCD WORKING-SET SWIZZLE. Evidence: FETCH 60 MB vs ~20 MB ideal (3x),
//     grid 768 = 3 blocks/CU exactly (grid-limited occupancy), all pipes
//     <25% busy => latency-bound on k/vt B-frag loads that miss the per-XCD
//     4 MB L2 (linear id%8 = bx%8 spreads ALL 48 bh over every XCD:
//     12.6 MB >> 4 MB). Remap flat id f so each XCD (f&7, assuming
//     round-robin dispatch) owns 6 consecutive bh: working set
//     6x256KB k/vt + 1.2MB pos = 2.7 MB < 4 MB. Bijective: g=f&7, s=f>>3,
//     bh=g*6+s/16, n0=(s&15)*64. Validation signal: FETCH_SIZE ~60->~30 MB.
//
//  2. T14 STAGE SPLIT. Next tile's pos-band rows are global-loaded into
//     registers right after S1 (overlapping T1/T2/S_qk/gather/PV compute,
//     ~thousands of cycles) and written to LDS at the next iteration's S0.
//     Removes the serialized stage-load latency (~300cy x 16 tiles) from
//     the per-tile critical path. +32 VGPR in flight (76 -> ~110 < 168 cap
//     for 3 waves/SIMD; no spill expected -- watch WRITE_SIZE).
//
// R4/R5 lessons honored: NO BSW swizzle (cost > benefit), NO direct-global
// pos B-frags (latency on MFMA path), register-lean accumulators.
// -----------------------------------------------------------------------------
#define ASTR 72  // LDS row stride in shorts (144 B): 16B-aligned, 2-way-free banks

__global__ __launch_bounds__(256, 3) void attn_fused(
    const unsigned short* __restrict__ q, const unsigned short* __restrict__ k,
    const unsigned short* __restrict__ vt, const unsigned short* __restrict__ pk,
    const unsigned short* __restrict__ pq, unsigned short* __restrict__ ao) {
  __shared__ __align__(16) unsigned short band1[128][ASTR];  // pk band, then T1^T
  __shared__ __align__(16) unsigned short band2[128][ASTR];  // pq band, then T2^T
  __shared__ __align__(16) unsigned short Ps[64][ASTR];

  // XCD working-set remap: flat id -> (bh, n0) so each XCD owns 6 bh.
  const int f = blockIdx.x + (blockIdx.y << 4);  // hw linear id, 0..767
  const int g = f & 7, s = f >> 3;               // XCD group, slot
  const int bh = g * 6 + (s >> 4);
  const int n0 = (s & 15) * 64;
  const int h = bh % 6, b = bh / 6;
  const int t = threadIdx.x;
  const int lane = t & 63, w = t >> 6;
  const int li = lane & 15, quad = lane >> 4;

  const unsigned short* qb = q + ((size_t)bh << 16);
  const unsigned short* kb = k + ((size_t)bh << 16);
  const unsigned short* vb = vt + ((size_t)bh << 16);
  const unsigned short* pkh = pk + (size_t)h * 49152;
  const unsigned short* pqh = pq + (size_t)h * 49152;

  // q A-frags: loaded once (q pre-scaled by INV_SCALE)
  short8 aq0 = *(const short8*)(qb + (size_t)(n0 + w * 16 + li) * 64 + quad * 8);
  short8 aq1 = *(const short8*)(qb + (size_t)(n0 + w * 16 + li) * 64 + 32 + quad * 8);

  float l_part[4] = {0.f, 0.f, 0.f, 0.f};
  v4f o[4] = {};

  // T14 stage split: per-thread staging slice (row sr, 32-short quarter sc).
  const int sr = t >> 1, sc = (t & 1) * 32;
  short8 st1[4], st2[4];
  {
    int src = n0 - 0 - 63 + 384 + sr;
    src = src < 0 ? 0 : (src > 767 ? 767 : src);
    const unsigned short* p1 = pkh + (size_t)src * 64 + sc;
    const unsigned short* p2 = pqh + (size_t)src * 64 + sc;
#pragma unroll
    for (int ss = 0; ss < 4; ++ss) {
      st1[ss] = *(const short8*)(p1 + ss * 8);
      st2[ss] = *(const short8*)(p2 + ss * 8);
    }
  }

  for (int j0 = 0; j0 < 1024; j0 += 64) {
    __syncthreads();  // S0: prev gather reads done; band buffers free
    // ---- write pre-fetched pos bands to LDS ----
#pragma unroll
    for (int ss = 0; ss < 4; ++ss) {
      *(short8*)&band1[sr][sc + ss * 8] = st1[ss];
      *(short8*)&band2[sr][sc + ss * 8] = st2[ss];
    }
    __syncthreads();  // S1: bands visible

    // ---- issue next tile's stage loads (consumed at next S0) ----
    {
      int src = n0 - (j0 + 64) - 63 + 384 + sr;  // last iter: clamped, unused
      src = src < 0 ? 0 : (src > 767 ? 767 : src);
      const unsigned short* p1 = pkh + (size_t)src * 64 + sc;
      const unsigned short* p2 = pqh + (size_t)src * 64 + sc;
#pragma unroll
      for (int ss = 0; ss < 4; ++ss) {
        st1[ss] = *(const short8*)(p1 + ss * 8);
        st2[ss] = *(const short8*)(p2 + ss * 8);
      }
    }

    // k A-frags for T2 (rows j0 + w*16 + li)
    short8 ak0 = *(const short8*)(kb + (size_t)(j0 + w * 16 + li) * 64 + quad * 8);
    short8 ak1 = *(const short8*)(kb + (size_t)(j0 + w * 16 + li) * 64 + 32 + quad * 8);

    // ---- T1 = q' @ pkband^T, T2 = k @ pq'band^T (B-frags from LDS) ----
    v4f t1a[8] = {}, t2a[8] = {};
#pragma unroll
    for (int ct = 0; ct < 8; ++ct) {
      short8 b10 = *(const short8*)&band1[ct * 16 + li][quad * 8];
      short8 b11 = *(const short8*)&band1[ct * 16 + li][32 + quad * 8];
      t1a[ct] = __builtin_amdgcn_mfma_f32_16x16x32_bf16(aq0, b10, t1a[ct], 0, 0, 0);
      t1a[ct] = __builtin_amdgcn_mfma_f32_16x16x32_bf16(aq1, b11, t1a[ct], 0, 0, 0);
      short8 b20 = *(const short8*)&band2[ct * 16 + li][quad * 8];
      short8 b21 = *(const short8*)&band2[ct * 16 + li][32 + quad * 8];
      t2a[ct] = __builtin_amdgcn_mfma_f32_16x16x32_bf16(ak0, b20, t2a[ct], 0, 0, 0);
      t2a[ct] = __builtin_amdgcn_mfma_f32_16x16x32_bf16(ak1, b21, t2a[ct], 0, 0, 0);
    }
    __syncthreads();  // S2: all band B-frag reads complete before overwrite

    // ---- write T1^T/T2^T into the (dead) band buffers ----
#pragma unroll
    for (int ct = 0; ct < 8; ++ct) {
      us4 p1 = {f2bf(t1a[ct][0]), f2bf(t1a[ct][1]), f2bf(t1a[ct][2]), f2bf(t1a[ct][3])};
      us4 p2 = {f2bf(t2a[ct][0]), f2bf(t2a[ct][1]), f2bf(t2a[ct][2]), f2bf(t2a[ct][3])};
      *(us4*)&band1[ct * 16 + li][w * 16 + quad * 4] = p1;
      *(us4*)&band2[ct * 16 + li][w * 16 + quad * 4] = p2;
    }
    // ---- S_qk (B-frags = k rows direct from global/L1) ----
    v4f sqk[4] = {};
#pragma unroll
    for (int nt = 0; nt < 4; ++nt) {
      short8 b0 = *(const short8*)(kb + (size_t)(j0 + nt * 16 + li) * 64 + quad * 8);
      short8 b1 = *(const short8*)(kb + (size_t)(j0 + nt * 16 + li) * 64 + 32 + quad * 8);
      sqk[nt] = __builtin_amdgcn_mfma_f32_16x16x32_bf16(aq0, b0, sqk[nt], 0, 0, 0);
      sqk[nt] = __builtin_amdgcn_mfma_f32_16x16x32_bf16(aq1, b1, sqk[nt], 0, 0, 0);
    }
    __syncthreads();  // S3: T^T visible cross-wave

    // ---- gather + exp (scale pre-folded) + Ps ----
#pragma unroll
    for (int nt = 0; nt < 4; ++nt) {
      int jl = nt * 16 + li;
#pragma unroll
      for (int i = 0; i < 4; ++i) {
        int nl = w * 16 + quad * 4 + i;
        int r = nl - jl + 63;
        float s2 = sqk[nt][i] + bf2f(band1[r][nl]) + bf2f(band2[r][jl]);
        float p = __expf(s2);
        l_part[i] += p;
        Ps[nl][jl] = f2bf(p);
      }
    }
    // ---- PV (A-frag Ps: same-wave rows; B-frag vt direct from global) ----
#pragma unroll
    for (int kst = 0; kst < 2; ++kst) {
      short8 ap = *(const short8*)&Ps[w * 16 + li][kst * 32 + quad * 8];
#pragma unroll
      for (int nt = 0; nt < 4; ++nt) {
        short8 bv2 = *(const short8*)(vb + (size_t)(nt * 16 + li) * 1024 + j0 + kst * 32 + quad * 8);
        o[nt] = __builtin_amdgcn_mfma_f32_16x16x32_bf16(ap, bv2, o[nt], 0, 0, 0);
      }
    }
  }

  // final: reduce l across the 16 col-lanes, normalize, store (B,N,C) bf16
#pragma unroll
  for (int i = 0; i < 4; ++i) {
    float l = l_part[i];
    l += __shfl_xor(l, 1);
    l += __shfl_xor(l, 2);
    l += __shfl_xor(l, 4);
    l += __shfl_xor(l, 8);
    float inv_l = 1.f / l;
    int nl = w * 16 + quad * 4 + i;
#pragma unroll
    for (int nt = 0; nt < 4; ++nt)
      ao[((size_t)(b * 1024 + n0 + nl)) * 384 + h * 64 + nt * 16 + li] =
          f2bf(o[nt][i] * inv_l);
  }
}

// -----------------------------------------------------------------------------
extern "C" void kernel_launch(void* const* d_in, const int* in_sizes, int n_in,
                              void* d_out, int out_size, void* d_ws,
                              size_t ws_size, hipStream_t stream) {
  const float* x   = (const float*)d_in[0];
  const float* re  = (const float*)d_in[2];
  const float* Wq  = (const float*)d_in[3];
  const float* bq  = (const float*)d_in[4];
  const float* Wk  = (const float*)d_in[5];
  const float* bk  = (const float*)d_in[6];
  const float* Wv  = (const float*)d_in[7];
  const float* bv  = (const float*)d_in[8];
  const float* Wpk = (const float*)d_in[9];
  const float* bpk = (const float*)d_in[10];
  const float* Wpq = (const float*)d_in[11];
  const float* bpq = (const float*)d_in[12];
  const float* Wo  = (const float*)d_in[13];
  const float* bo  = (const float*)d_in[14];
  float* out = (float*)d_out;

  unsigned short* ws = (unsigned short*)d_ws;
  unsigned short* Wt  = ws;                 // 6*384*384
  unsigned short* qw  = Wt + 884736;        // 48*1024*64 (pre-scaled)
  unsigned short* kw  = qw + 3145728;
  unsigned short* vtw = kw + 3145728;       // (B,H,D,N)
  unsigned short* pkw = vtw + 3145728;      // 6*768*64
  unsigned short* pqw = pkw + 294912;       // (pre-scaled)
  unsigned short* aow = pqw + 294912;       // 8192*384 bf16

  transpose_w<<<dim3(36, 6), 256, 0, stream>>>(Wq, Wk, Wv, Wpk, Wpq, Wo, Wt);
  proj_all<<<dim3(128, 30), 256, 0, stream>>>(x, re, Wt, bq, bk, bv, bpk, bpq,
                                              qw, kw, vtw, pkw, pqw);
  attn_fused<<<dim3(16, 48), 256, 0, stream>>>(qw, kw, vtw, pkw, pqw, aow);
  out_gemm<<<dim3(128, 6), 256, 0, stream>>>(aow, Wt + 5 * 147456, bo, out);
}

// Round 9
// 260.373 us; speedup vs baseline: 1.4596x; 1.0433x over previous
//
#include <hip/hip_runtime.h>
#include <math.h>

typedef __attribute__((ext_vector_type(8))) short short8;
typedef __attribute__((ext_vector_type(4))) float v4f;
typedef __attribute__((ext_vector_type(4))) unsigned short us4;

#define INV_SCALE 0.07216878364870322f  // 1/sqrt(64*3)

__device__ __forceinline__ unsigned short f2bf(float f) {
  unsigned u = __builtin_bit_cast(unsigned, f);
  u = (u + 0x7FFFu + ((u >> 16) & 1u)) >> 16;  // RNE
  return (unsigned short)u;
}
__device__ __forceinline__ float bf2f(unsigned short h) {
  unsigned u = ((unsigned)h) << 16;
  return __builtin_bit_cast(float, u);
}

enum { OM_PLAIN = 0, OM_Q = 1, OM_K = 2, OM_VT = 3, OM_PK = 4, OM_PQ = 5 };

// -----------------------------------------------------------------------------
// One-time: x (8192x384) and re (768x384) fp32 -> bf16, so the GEMM A-reads
// are half-width and convert-free. Same RNE as the old inline path ->
// bit-identical results. Grid 1680 x 256, 8 elems/thread.
// -----------------------------------------------------------------------------
__global__ __launch_bounds__(256) void cvt_bf16(
    const float* __restrict__ x, const float* __restrict__ re,
    unsigned short* __restrict__ xb, unsigned short* __restrict__ reb) {
  size_t idx = ((size_t)blockIdx.x * 256 + threadIdx.x) * 8;
  const float* src;
  unsigned short* dst;
  if (idx < 3145728) {
    src = x + idx; dst = xb + idx;
  } else {
    size_t r = idx - 3145728;
    if (r >= 294912) return;
    src = re + r; dst = reb + r;
  }
  float4 u0 = *(const float4*)src;
  float4 u1 = *(const float4*)(src + 4);
  short8 v;
  v[0] = (short)f2bf(u0.x); v[1] = (short)f2bf(u0.y);
  v[2] = (short)f2bf(u0.z); v[3] = (short)f2bf(u0.w);
  v[4] = (short)f2bf(u1.x); v[5] = (short)f2bf(u1.y);
  v[6] = (short)f2bf(u1.z); v[7] = (short)f2bf(u1.w);
  *(short8*)dst = v;
}

// -----------------------------------------------------------------------------
// One-time: transpose all 6 weight matrices (384x384 fp32 [k][n]) to bf16
// [n][k] so GEMM B reads are contiguous. Wt = 6 x 384 x 384 bf16.
// -----------------------------------------------------------------------------
__global__ __launch_bounds__(256) void transpose_w(
    const float* __restrict__ Wq, const float* __restrict__ Wk,
    const float* __restrict__ Wv, const float* __restrict__ Wpk,
    const float* __restrict__ Wpq, const float* __restrict__ Wo,
    unsigned short* __restrict__ Wt) {
  __shared__ unsigned short Ts[64][68];
  const int mat = blockIdx.y;
  const float* W = mat == 0 ? Wq : mat == 1 ? Wk : mat == 2 ? Wv
                 : mat == 3 ? Wpk : mat == 4 ? Wpq : Wo;
  const int tk = (blockIdx.x % 6) * 64, tn = (blockIdx.x / 6) * 64;
  const int t = threadIdx.x;
#pragma unroll
  for (int it = 0; it < 4; ++it) {
    int r = (t >> 4) + it * 16, c = (t & 15) * 4;
    float4 v = *(const float4*)(W + (size_t)(tk + r) * 384 + tn + c);
    us4 p = {f2bf(v.x), f2bf(v.y), f2bf(v.z), f2bf(v.w)};
    *(us4*)&Ts[r][c] = p;
  }
  __syncthreads();
  unsigned short* out = Wt + (size_t)mat * 147456;
#pragma unroll
  for (int it = 0; it < 2; ++it) {
    int n = (t >> 3) + it * 32, kc = (t & 7) * 8;
    unsigned short tmp[8];
#pragma unroll
    for (int j = 0; j < 8; ++j) tmp[j] = Ts[kc + j][n];
    *(short8*)(out + (size_t)(tn + n) * 384 + tk + kc) = *(short8*)tmp;
  }
}

// -----------------------------------------------------------------------------
// GEMM body, ROUND-9 PANEL LOOP: A-frags (bf16) loaded ONCE per block into
// registers; loop NP n-panels restaging only B (L2-resident Wt). Kills the
// A-refetch: old structure re-read A once per n-panel (x: 226 MB fp32 total);
// now 1 read per (m-block, GEMM, panel-group) = 38 MB bf16.
// Restage overlaps epilogue stores (stores don't touch Bs).
// -----------------------------------------------------------------------------
template <int OMODE, int NP>
__device__ __forceinline__ void pgemm_body(
    const unsigned short* __restrict__ A, const unsigned short* __restrict__ Bt,
    const float* __restrict__ bias, void* __restrict__ out,
    int m0, int ng0, float scale, unsigned short (*Bs)[392]) {
  const int t = threadIdx.x;
  const int lane = t & 63, w = t >> 6, li = lane & 15, quad = lane >> 4;
  const int row = m0 + w * 16 + li;
  const int sr = t >> 2, scq = (t & 3) * 96;

  // stage first panel
#pragma unroll
  for (int i = 0; i < 12; ++i)
    *(short8*)&Bs[sr][scq + i * 8] =
        *(const short8*)(Bt + (size_t)(ng0 * 64 + sr) * 384 + scq + i * 8);

  // A-frags: once per block (overlaps staging latency)
  short8 afr[12];
#pragma unroll
  for (int kk = 0; kk < 12; ++kk)
    afr[kk] = *(const short8*)(A + (size_t)row * 384 + kk * 32 + quad * 8);

#pragma unroll
  for (int pp = 0; pp < NP; ++pp) {
    __syncthreads();  // stage of panel pp visible
    v4f acc[4] = {};
#pragma unroll
    for (int kk = 0; kk < 12; ++kk) {
#pragma unroll
      for (int nt = 0; nt < 4; ++nt) {
        short8 bf = *(const short8*)&Bs[nt * 16 + li][kk * 32 + quad * 8];
        acc[nt] = __builtin_amdgcn_mfma_f32_16x16x32_bf16(afr[kk], bf, acc[nt], 0, 0, 0);
      }
    }
    __syncthreads();  // all Bs reads done; free for restage
    if (pp + 1 < NP) {
#pragma unroll
      for (int i = 0; i < 12; ++i)
        *(short8*)&Bs[sr][scq + i * 8] =
            *(const short8*)(Bt + (size_t)((ng0 + pp + 1) * 64 + sr) * 384 + scq + i * 8);
    }
    // epilogue for panel pp (overlaps the restage)
    const int n0 = (ng0 + pp) * 64;
#pragma unroll
    for (int nt = 0; nt < 4; ++nt) {
      int col = n0 + nt * 16 + li;
      float bv = bias[col];
      int h = col >> 6, d = col & 63;
#pragma unroll
      for (int i = 0; i < 4; ++i) {
        int orow = m0 + w * 16 + quad * 4 + i;
        float val = (acc[nt][i] + bv) * scale;
        if constexpr (OMODE == OM_PLAIN) {
          ((float*)out)[(size_t)orow * 384 + col] = val;
        } else if constexpr (OMODE == OM_Q || OMODE == OM_K) {
          int b = orow >> 10, n = orow & 1023;
          ((unsigned short*)out)[((size_t)(b * 6 + h) << 16) + (n << 6) + d] = f2bf(val);
        } else if constexpr (OMODE == OM_VT) {
          int b = orow >> 10, n = orow & 1023;
          ((unsigned short*)out)[((size_t)(b * 6 + h) << 16) + (d << 10) + n] = f2bf(val);
        } else {  // OM_PK / OM_PQ: [h][p][d]
          ((unsigned short*)out)[(size_t)h * 49152 + (size_t)orow * 64 + d] = f2bf(val);
        }
      }
    }
  }
}

// Grid (128, 10): y<6 -> which=y>>1 (q/k/v), ng0=(y&1)*3, M=8192;
// y>=6 -> p=y-6: which=3+(p>>1) (pk/pq), ng0=(p&1)*3, M=768 (x<12).
__global__ __launch_bounds__(256, 3) void proj_all(
    const unsigned short* __restrict__ xb, const unsigned short* __restrict__ reb,
    const unsigned short* __restrict__ Wt,
    const float* __restrict__ bq, const float* __restrict__ bk,
    const float* __restrict__ bv, const float* __restrict__ bpk,
    const float* __restrict__ bpq,
    unsigned short* __restrict__ qw, unsigned short* __restrict__ kw,
    unsigned short* __restrict__ vtw, unsigned short* __restrict__ pkw,
    unsigned short* __restrict__ pqw) {
  __shared__ __align__(16) unsigned short Bs[64][392];
  const int y = blockIdx.y;
  const int m0 = blockIdx.x * 64;
  int which, ng0;
  if (y < 6) {
    which = y >> 1; ng0 = (y & 1) * 3;
  } else {
    int p = y - 6;
    which = 3 + (p >> 1); ng0 = (p & 1) * 3;
    if (m0 >= 768) return;
  }
  const unsigned short* A = which < 3 ? xb : reb;
  const unsigned short* Bt = Wt + (size_t)which * 147456;
  switch (which) {
    case 0: pgemm_body<OM_Q, 3>(A, Bt, bq,  qw,  m0, ng0, INV_SCALE, Bs); break;
    case 1: pgemm_body<OM_K, 3>(A, Bt, bk,  kw,  m0, ng0, 1.f, Bs); break;
    case 2: pgemm_body<OM_VT,3>(A, Bt, bv,  vtw, m0, ng0, 1.f, Bs); break;
    case 3: pgemm_body<OM_PK,3>(A, Bt, bpk, pkw, m0, ng0, 1.f, Bs); break;
    default: pgemm_body<OM_PQ,3>(A, Bt, bpq, pqw, m0, ng0, INV_SCALE, Bs); break;
  }
}

// Grid (128, 2): ng0 = y*3, 3 panels per block; A (aow bf16) read 2x not 6x.
__global__ __launch_bounds__(256, 3) void out_gemm(
    const unsigned short* __restrict__ ao, const unsigned short* __restrict__ Bt,
    const float* __restrict__ bo, float* __restrict__ out) {
  __shared__ __align__(16) unsigned short Bs[64][392];
  pgemm_body<OM_PLAIN, 3>(ao, Bt, bo, out,
                          blockIdx.x * 64, blockIdx.y * 3, 1.f, Bs);
}

// -----------------------------------------------------------------------------
// Fused disentangled attention — ROUND-8 KERNEL VERBATIM (its best measured:
// 140.7 us, FETCH 14.6 MB). XCD working-set swizzle (validated: FETCH 60->14.6
// MB) + T14 stage split on the 146 us ROUND-4 structure (ASTR=72, LDS band
// staging, 4 barriers, register-lean). Do not touch.
// -----------------------------------------------------------------------------
#define ASTR 72  // LDS row stride in shorts (144 B): 16B-aligned, 2-way-free banks

__global__ __launch_bounds__(256, 3) void attn_fused(
    const unsigned short* __restrict__ q, const unsigned short* __restrict__ k,
    const unsigned short* __restrict__ vt, const unsigned short* __restrict__ pk,
    const unsigned short* __restrict__ pq, unsigned short* __restrict__ ao) {
  __shared__ __align__(16) unsigned short band1[128][ASTR];  // pk band, then T1^T
  __shared__ __align__(16) unsigned short band2[128][ASTR];  // pq band, then T2^T
  __shared__ __align__(16) unsigned short Ps[64][ASTR];

  // XCD working-set remap: flat id -> (bh, n0) so each XCD owns 6 bh.
  const int f = blockIdx.x + (blockIdx.y << 4);  // hw linear id, 0..767
  const int g = f & 7, s = f >> 3;               // XCD group, slot
  const int bh = g * 6 + (s >> 4);
  const int n0 = (s & 15) * 64;
  const int h = bh % 6, b = bh / 6;
  const int t = threadIdx.x;
  const int lane = t & 63, w = t >> 6;
  const int li = lane & 15, quad = lane >> 4;

  const unsigned short* qb = q + ((size_t)bh << 16);
  const unsigned short* kb = k + ((size_t)bh << 16);
  const unsigned short* vb = vt + ((size_t)bh << 16);
  const unsigned short* pkh = pk + (size_t)h * 49152;
  const unsigned short* pqh = pq + (size_t)h * 49152;

  // q A-frags: loaded once (q pre-scaled by INV_SCALE)
  short8 aq0 = *(const short8*)(qb + (size_t)(n0 + w * 16 + li) * 64 + quad * 8);
  short8 aq1 = *(const short8*)(qb + (size_t)(n0 + w * 16 + li) * 64 + 32 + quad * 8);

  float l_part[4] = {0.f, 0.f, 0.f, 0.f};
  v4f o[4] = {};

  // T14 stage split: per-thread staging slice (row sr, 32-short quarter sc).
  const int sr = t >> 1, sc = (t & 1) * 32;
  short8 st1[4], st2[4];
  {
    int src = n0 - 0 - 63 + 384 + sr;
    src = src < 0 ? 0 : (src > 767 ? 767 : src);
    const unsigned short* p1 = pkh + (size_t)src * 64 + sc;
    const unsigned short* p2 = pqh + (size_t)src * 64 + sc;
#pragma unroll
    for (int ss = 0; ss < 4; ++ss) {
      st1[ss] = *(const short8*)(p1 + ss * 8);
      st2[ss] = *(const short8*)(p2 + ss * 8);
    }
  }

  for (int j0 = 0; j0 < 1024; j0 += 64) {
    __syncthreads();  // S0: prev gather reads done; band buffers free
    // ---- write pre-fetched pos bands to LDS ----
#pragma unroll
    for (int ss = 0; ss < 4; ++ss) {
      *(short8*)&band1[sr][sc + ss * 8] = st1[ss];
      *(short8*)&band2[sr][sc + ss * 8] = st2[ss];
    }
    __syncthreads();  // S1: bands visible

    // ---- issue next tile's stage loads (consumed at next S0) ----
    {
      int src = n0 - (j0 + 64) - 63 + 384 + sr;  // last iter: clamped, unused
      src = src < 0 ? 0 : (src > 767 ? 767 : src);
      const unsigned short* p1 = pkh + (size_t)src * 64 + sc;
      const unsigned short* p2 = pqh + (size_t)src * 64 + sc;
#pragma unroll
      for (int ss = 0; ss < 4; ++ss) {
        st1[ss] = *(const short8*)(p1 + ss * 8);
        st2[ss] = *(const short8*)(p2 + ss * 8);
      }
    }

    // k A-frags for T2 (rows j0 + w*16 + li)
    short8 ak0 = *(const short8*)(kb + (size_t)(j0 + w * 16 + li) * 64 + quad * 8);
    short8 ak1 = *(const short8*)(kb + (size_t)(j0 + w * 16 + li) * 64 + 32 + quad * 8);

    // ---- T1 = q' @ pkband^T, T2 = k @ pq'band^T (B-frags from LDS) ----
    v4f t1a[8] = {}, t2a[8] = {};
#pragma unroll
    for (int ct = 0; ct < 8; ++ct) {
      short8 b10 = *(const short8*)&band1[ct * 16 + li][quad * 8];
      short8 b11 = *(const short8*)&band1[ct * 16 + li][32 + quad * 8];
      t1a[ct] = __builtin_amdgcn_mfma_f32_16x16x32_bf16(aq0, b10, t1a[ct], 0, 0, 0);
      t1a[ct] = __builtin_amdgcn_mfma_f32_16x16x32_bf16(aq1, b11, t1a[ct], 0, 0, 0);
      short8 b20 = *(const short8*)&band2[ct * 16 + li][quad * 8];
      short8 b21 = *(const short8*)&band2[ct * 16 + li][32 + quad * 8];
      t2a[ct] = __builtin_amdgcn_mfma_f32_16x16x32_bf16(ak0, b20, t2a[ct], 0, 0, 0);
      t2a[ct] = __builtin_amdgcn_mfma_f32_16x16x32_bf16(ak1, b21, t2a[ct], 0, 0, 0);
    }
    __syncthreads();  // S2: all band B-frag reads complete before overwrite

    // ---- write T1^T/T2^T into the (dead) band buffers ----
#pragma unroll
    for (int ct = 0; ct < 8; ++ct) {
      us4 p1 = {f2bf(t1a[ct][0]), f2bf(t1a[ct][1]), f2bf(t1a[ct][2]), f2bf(t1a[ct][3])};
      us4 p2 = {f2bf(t2a[ct][0]), f2bf(t2a[ct][1]), f2bf(t2a[ct][2]), f2bf(t2a[ct][3])};
      *(us4*)&band1[ct * 16 + li][w * 16 + quad * 4] = p1;
      *(us4*)&band2[ct * 16 + li][w * 16 + quad * 4] = p2;
    }
    // ---- S_qk (B-frags = k rows direct from global/L1) ----
    v4f sqk[4] = {};
#pragma unroll
    for (int nt = 0; nt < 4; ++nt) {
      short8 b0 = *(const short8*)(kb + (size_t)(j0 + nt * 16 + li) * 64 + quad * 8);
      short8 b1 = *(const short8*)(kb + (size_t)(j0 + nt * 16 + li) * 64 + 32 + quad * 8);
      sqk[nt] = __builtin_amdgcn_mfma_f32_16x16x32_bf16(aq0, b0, sqk[nt], 0, 0, 0);
      sqk[nt] = __builtin_amdgcn_mfma_f32_16x16x32_bf16(aq1, b1, sqk[nt], 0, 0, 0);
    }
    __syncthreads();  // S3: T^T visible cross-wave

    // ---- gather + exp (scale pre-folded) + Ps ----
#pragma unroll
    for (int nt = 0; nt < 4; ++nt) {
      int jl = nt * 16 + li;
#pragma unroll
      for (int i = 0; i < 4; ++i) {
        int nl = w * 16 + quad * 4 + i;
        int r = nl - jl + 63;
        float s2 = sqk[nt][i] + bf2f(band1[r][nl]) + bf2f(band2[r][jl]);
        float p = __expf(s2);
        l_part[i] += p;
        Ps[nl][jl] = f2bf(p);
      }
    }
    // ---- PV (A-frag Ps: same-wave rows; B-frag vt direct from global) ----
#pragma unroll
    for (int kst = 0; kst < 2; ++kst) {
      short8 ap = *(const short8*)&Ps[w * 16 + li][kst * 32 + quad * 8];
#pragma unroll
      for (int nt = 0; nt < 4; ++nt) {
        short8 bv2 = *(const short8*)(vb + (size_t)(nt * 16 + li) * 1024 + j0 + kst * 32 + quad * 8);
        o[nt] = __builtin_amdgcn_mfma_f32_16x16x32_bf16(ap, bv2, o[nt], 0, 0, 0);
      }
    }
  }

  // final: reduce l across the 16 col-lanes, normalize, store (B,N,C) bf16
#pragma unroll
  for (int i = 0; i < 4; ++i) {
    float l = l_part[i];
    l += __shfl_xor(l, 1);
    l += __shfl_xor(l, 2);
    l += __shfl_xor(l, 4);
    l += __shfl_xor(l, 8);
    float inv_l = 1.f / l;
    int nl = w * 16 + quad * 4 + i;
#pragma unroll
    for (int nt = 0; nt < 4; ++nt)
      ao[((size_t)(b * 1024 + n0 + nl)) * 384 + h * 64 + nt * 16 + li] =
          f2bf(o[nt][i] * inv_l);
  }
}

// -----------------------------------------------------------------------------
extern "C" void kernel_launch(void* const* d_in, const int* in_sizes, int n_in,
                              void* d_out, int out_size, void* d_ws,
                              size_t ws_size, hipStream_t stream) {
  const float* x   = (const float*)d_in[0];
  const float* re  = (const float*)d_in[2];
  const float* Wq  = (const float*)d_in[3];
  const float* bq  = (const float*)d_in[4];
  const float* Wk  = (const float*)d_in[5];
  const float* bk  = (const float*)d_in[6];
  const float* Wv  = (const float*)d_in[7];
  const float* bv  = (const float*)d_in[8];
  const float* Wpk = (const float*)d_in[9];
  const float* bpk = (const float*)d_in[10];
  const float* Wpq = (const float*)d_in[11];
  const float* bpq = (const float*)d_in[12];
  const float* Wo  = (const float*)d_in[13];
  const float* bo  = (const float*)d_in[14];
  float* out = (float*)d_out;

  unsigned short* ws = (unsigned short*)d_ws;
  unsigned short* Wt  = ws;                 // 6*384*384
  unsigned short* qw  = Wt + 884736;        // 48*1024*64 (pre-scaled)
  unsigned short* kw  = qw + 3145728;
  unsigned short* vtw = kw + 3145728;       // (B,H,D,N)
  unsigned short* pkw = vtw + 3145728;      // 6*768*64
  unsigned short* pqw = pkw + 294912;       // (pre-scaled)
  unsigned short* aow = pqw + 294912;       // 8192*384 bf16
  unsigned short* xb  = aow + 3145728;      // 8192*384 bf16
  unsigned short* reb = xb + 3145728;       // 768*384 bf16  (end ~41.3 MB)

  cvt_bf16<<<dim3(1680), 256, 0, stream>>>(x, re, xb, reb);
  transpose_w<<<dim3(36, 6), 256, 0, stream>>>(Wq, Wk, Wv, Wpk, Wpq, Wo, Wt);
  proj_all<<<dim3(128, 10), 256, 0, stream>>>(xb, reb, Wt, bq, bk, bv, bpk, bpq,
                                              qw, kw, vtw, pkw, pqw);
  attn_fused<<<dim3(16, 48), 256, 0, stream>>>(qw, kw, vtw, pkw, pqw, aow);
  out_gemm<<<dim3(128, 2), 256, 0, stream>>>(aow, Wt + 5 * 147456, bo, out);
}